// Round 4
// baseline (657.654 us; speedup 1.0000x reference)
//
#include <hip/hip_runtime.h>

// ---------------------------------------------------------------------------
// Single fused persistent kernel: 256 blocks x 256 threads (1 block/CU),
// manual grid barriers (init-free, works for any initial ws contents).
// No global atomics on hot paths (K-split partials + inline sums instead).
// R4 fix: restored grid-stride loops in S0 c2-preload and S7 (400 outputs
// vs 256 threads — R3 silently dropped f2w[256..399]).
// ---------------------------------------------------------------------------

#define GRID 256
#define NT   256

// dims
#define NN 64
#define EE 128
#define GG 4
#define D0 9
#define H1 2000
#define H2 500
#define H3 100
#define FF1 1000
#define FF2 100
#define FF3 50
#define KDIM 384  // 64 nodes * 6 channels (4 edge-attr + 1 bias-row + 1 root)

// ws layout (float indices). ws[0..255]=flags, ws[256]=release word.
#define OFF_A    272       // 64*384   = 24576
#define OFF_Y    24848     // 64*54    = 3456
#define OFF_PRE1 28304     // 64*2000  = 128000 (raw pre-activation, b1 added)
#define OFF_N2P  156304    // 5 * 384*500 = 960000 (K-split partials)
#define OFF_PRE2 1116304   // 64*500   = 32000 (raw, b2 added)
#define OFF_N3P  1148304   // 5 * 384*100 = 192000
#define OFF_PRE3 1340304   // 64*100   = 6400 (raw, b3 added)
#define OFF_F1   1346704   // 4*1000 (post-relu)
#define OFF_F2   1350704   // 4*100  (c2 preloaded + atomic partial adds)
// total 1,351,104 floats = 5.40 MB

__device__ __forceinline__ float4 relu4(float4 v) {
    v.x = v.x > 0.f ? v.x : 0.f; v.y = v.y > 0.f ? v.y : 0.f;
    v.z = v.z > 0.f ? v.z : 0.f; v.w = v.w > 0.f ? v.w : 0.f;
    return v;
}

// Init-free grid barrier: block j writes flags[j]=phase; block 0 scans, then
// publishes release=phase. Phases 1..8 never collide with 0xAAAAAAAA poison
// or any stale value from a previous launch (ws re-poisoned every call).
__device__ __forceinline__ void gbar(unsigned phase, unsigned* flags,
                                     unsigned* rel) {
    __syncthreads();
    if (blockIdx.x == 0) {
        if (threadIdx.x < 64) {
            for (int j = 1 + (int)threadIdx.x; j < GRID; j += 64) {
                while (__hip_atomic_load(&flags[j], __ATOMIC_ACQUIRE,
                                         __HIP_MEMORY_SCOPE_AGENT) != phase)
                    __builtin_amdgcn_s_sleep(1);
            }
        }
        __syncthreads();
        if (threadIdx.x == 0)
            __hip_atomic_store(rel, phase, __ATOMIC_RELEASE,
                               __HIP_MEMORY_SCOPE_AGENT);
        __syncthreads();
    } else {
        if (threadIdx.x == 0) {
            __hip_atomic_store(&flags[blockIdx.x], phase, __ATOMIC_RELEASE,
                               __HIP_MEMORY_SCOPE_AGENT);
            while (__hip_atomic_load(rel, __ATOMIC_ACQUIRE,
                                     __HIP_MEMORY_SCOPE_AGENT) != phase)
                __builtin_amdgcn_s_sleep(1);
        }
        __syncthreads();
    }
}

__global__ __launch_bounds__(NT, 2) void fused_gnn(
    const float* __restrict__ x, const int* __restrict__ edge_index,
    const float* __restrict__ edge_attr, const int* __restrict__ batch,
    const float* __restrict__ We1, const float* __restrict__ be1,
    const float* __restrict__ root1, const float* __restrict__ b1,
    const float* __restrict__ We2, const float* __restrict__ be2,
    const float* __restrict__ root2, const float* __restrict__ b2,
    const float* __restrict__ We3, const float* __restrict__ be3,
    const float* __restrict__ root3, const float* __restrict__ b3,
    const float* __restrict__ W1, const float* __restrict__ c1,
    const float* __restrict__ W2, const float* __restrict__ c2,
    const float* __restrict__ W3, const float* __restrict__ c3,
    const float* __restrict__ W4, const float* __restrict__ c4,
    float* __restrict__ ws, float* __restrict__ out)
{
    __shared__ float smem[9600];  // 38.4 KB union; 1+ block/CU guaranteed

    unsigned* flags = (unsigned*)ws;
    unsigned* rel   = flags + GRID;
    const int bid = blockIdx.x, tid = threadIdx.x;
    const int tx = tid & 15, ty = tid >> 4;

    float* Ahat = ws + OFF_A;
    float* Yw   = ws + OFF_Y;
    float* pre1 = ws + OFF_PRE1;
    float* n2p  = ws + OFF_N2P;
    float* pre2 = ws + OFF_PRE2;
    float* n3p  = ws + OFF_N3P;
    float* pre3 = ws + OFF_PRE3;
    float* f1w  = ws + OFF_F1;
    float* f2w  = ws + OFF_F2;

    // ---------------- S0: A-hat, Y, f2 preload ----------------
    if (bid == 0) {
        for (int i = tid; i < NN * KDIM; i += NT) Ahat[i] = 0.f;
        __syncthreads();
        if (tid < EE) {
            int s = edge_index[tid], t = edge_index[EE + tid];
            float* row = Ahat + t * KDIM + s * 6;
            #pragma unroll
            for (int d = 0; d < 4; ++d) atomicAdd(row + d, edge_attr[tid * 4 + d]);
            atomicAdd(row + 4, 1.0f);
        }
        if (tid < NN) Ahat[tid * KDIM + tid * 6 + 5] = 1.0f;
    } else if (bid == 1) {
        float* Ys = smem;  // 64*54
        for (int i = tid; i < NN * 54; i += NT) Ys[i] = 0.f;
        __syncthreads();
        if (tid < EE) {
            int s = edge_index[tid], t = edge_index[EE + tid];
            float ea[4];
            #pragma unroll
            for (int d = 0; d < 4; ++d) ea[d] = edge_attr[tid * 4 + d];
            #pragma unroll
            for (int i = 0; i < D0; ++i) {
                float xv = x[s * D0 + i];
                #pragma unroll
                for (int d = 0; d < 4; ++d)
                    atomicAdd(&Ys[t * 54 + d * 9 + i], ea[d] * xv);
                atomicAdd(&Ys[t * 54 + 36 + i], xv);
            }
        }
        if (tid < NN) {
            #pragma unroll
            for (int i = 0; i < D0; ++i) Ys[tid * 54 + 45 + i] = x[tid * D0 + i];
        }
        __syncthreads();
        for (int i = tid; i < NN * 54; i += NT) Yw[i] = Ys[i];
    } else if (bid == 2) {
        for (int i = tid; i < GG * FF2; i += NT) f2w[i] = c2[i % FF2];
    }
    gbar(1, flags, rel);

    // ---------------- S1: pre1 = b1 + Y @ Wcat1 [64x54]@[54x2000] ----------
    if (bid < 32) {
        float* Ys = smem;           // 64*57 padded
        float* Bs = smem + 64 * 57; // 54*64
        const int o0 = bid * 64;
        const int w = (o0 + 64 <= H1) ? 64 : (H1 - o0);
        for (int i = tid; i < NN * 54; i += NT) {
            int u = i / 54, r = i - u * 54;
            Ys[u * 57 + r] = Yw[i];
        }
        for (int i = tid; i < 54 * 64; i += NT) {
            int r = i >> 6, c = i & 63;
            int d = r / 9, ii = r - d * 9;
            const float* rowp = ((d < 4) ? (We1 + d * (D0 * H1))
                                         : ((d == 4) ? be1 : root1)) + ii * H1;
            Bs[r * 64 + c] = (c < w) ? rowp[o0 + c] : 0.f;
        }
        __syncthreads();
        float acc[4][4] = {};
        #pragma unroll 6
        for (int r = 0; r < 54; ++r) {
            float a0 = Ys[(ty * 4 + 0) * 57 + r];
            float a1 = Ys[(ty * 4 + 1) * 57 + r];
            float a2 = Ys[(ty * 4 + 2) * 57 + r];
            float a3 = Ys[(ty * 4 + 3) * 57 + r];
            const float4 bv = *(const float4*)&Bs[r * 64 + tx * 4];
            acc[0][0] += a0 * bv.x; acc[0][1] += a0 * bv.y; acc[0][2] += a0 * bv.z; acc[0][3] += a0 * bv.w;
            acc[1][0] += a1 * bv.x; acc[1][1] += a1 * bv.y; acc[1][2] += a1 * bv.z; acc[1][3] += a1 * bv.w;
            acc[2][0] += a2 * bv.x; acc[2][1] += a2 * bv.y; acc[2][2] += a2 * bv.z; acc[2][3] += a2 * bv.w;
            acc[3][0] += a3 * bv.x; acc[3][1] += a3 * bv.y; acc[3][2] += a3 * bv.z; acc[3][3] += a3 * bv.w;
        }
        if (tx * 4 < w) {
            const float4 bb = *(const float4*)(b1 + o0 + tx * 4);
            #pragma unroll
            for (int i = 0; i < 4; ++i) {
                int u = ty * 4 + i;
                float4 v = make_float4(acc[i][0] + bb.x, acc[i][1] + bb.y,
                                       acc[i][2] + bb.z, acc[i][3] + bb.w);
                *(float4*)(pre1 + u * H1 + o0 + tx * 4) = v;
            }
        }
    }
    gbar(2, flags, rel);

    // ---------------- S2: n2p[s] = relu(pre1) @ Wcat2 (K-split 5) ----------
    // grid: 240 blocks = d(6) x ot(8) x s(5); tile 64x64, span 400 = 10x40
    if (bid < 240) {
        const int s = bid % 5, ot = (bid / 5) % 8, d = bid / 40;
        const float* Bsec = (d < 4) ? (We2 + (size_t)d * (H1 * H2))
                                    : ((d == 4) ? be2 : root2);
        const int o0 = ot * 64;
        const int w4 = (o0 + 64 <= H2) ? 16 : ((H2 - o0) >> 2);  // ot7: 13
        float* As = smem;            // 64 x 44
        float* Bs = smem + 64 * 44;  // 40 x 64
        float acc[4][4] = {};
        for (int it = 0; it < 10; ++it) {
            const int kb = s * 400 + it * 40;
            __syncthreads();
            for (int idx = tid; idx < 640; idx += NT) {
                int r = idx / 10, c4 = idx - r * 10;
                float4 v = relu4(*(const float4*)(pre1 + r * H1 + kb + c4 * 4));
                *(float4*)&As[r * 44 + c4 * 4] = v;
            }
            for (int idx = tid; idx < 640; idx += NT) {
                int k = idx >> 4, c4 = idx & 15;
                if (c4 < w4)
                    *(float4*)&Bs[k * 64 + c4 * 4] =
                        *(const float4*)(Bsec + (size_t)(kb + k) * H2 + o0 + c4 * 4);
            }
            __syncthreads();
            #pragma unroll 8
            for (int kk = 0; kk < 40; ++kk) {
                float a0 = As[(ty * 4 + 0) * 44 + kk];
                float a1 = As[(ty * 4 + 1) * 44 + kk];
                float a2 = As[(ty * 4 + 2) * 44 + kk];
                float a3 = As[(ty * 4 + 3) * 44 + kk];
                const float4 bv = *(const float4*)&Bs[kk * 64 + tx * 4];
                acc[0][0] += a0 * bv.x; acc[0][1] += a0 * bv.y; acc[0][2] += a0 * bv.z; acc[0][3] += a0 * bv.w;
                acc[1][0] += a1 * bv.x; acc[1][1] += a1 * bv.y; acc[1][2] += a1 * bv.z; acc[1][3] += a1 * bv.w;
                acc[2][0] += a2 * bv.x; acc[2][1] += a2 * bv.y; acc[2][2] += a2 * bv.z; acc[2][3] += a2 * bv.w;
                acc[3][0] += a3 * bv.x; acc[3][1] += a3 * bv.y; acc[3][2] += a3 * bv.z; acc[3][3] += a3 * bv.w;
            }
        }
        if (tx < w4) {
            float* dst = n2p + s * (KDIM * H2);
            #pragma unroll
            for (int i = 0; i < 4; ++i) {
                int u = ty * 4 + i;
                *(float4*)(dst + (u * 6 + d) * H2 + o0 + tx * 4) =
                    make_float4(acc[i][0], acc[i][1], acc[i][2], acc[i][3]);
            }
        }
    }
    gbar(3, flags, rel);

    // ---------------- S3: pre2 = b2 + Ahat @ sum_s n2p[s] ------------------
    // grid: 32 = ot(8) x r(4); block = rows 16 x cols 64, K=384 (8x48)
    if (bid < 32) {
        const int ot = bid >> 2, r = bid & 3;
        const int o0 = ot * 64;
        const int w4 = (o0 + 64 <= H2) ? 16 : ((H2 - o0) >> 2);
        float* As = smem;             // 16 x 388
        float* Bs = smem + 16 * 388;  // 48 x 64
        for (int idx = tid; idx < 16 * 96; idx += NT) {
            int rr = idx / 96, c4 = idx - rr * 96;
            *(float4*)&As[rr * 388 + c4 * 4] =
                *(const float4*)(Ahat + (r * 16 + rr) * KDIM + c4 * 4);
        }
        float acc[4] = {};
        for (int it = 0; it < 8; ++it) {
            const int kb = it * 48;
            __syncthreads();
            for (int idx = tid; idx < 48 * 16; idx += NT) {
                int k = idx >> 4, c4 = idx & 15;
                if (c4 < w4) {
                    const float* p = n2p + (kb + k) * H2 + o0 + c4 * 4;
                    float4 v0 = *(const float4*)(p);
                    float4 v1 = *(const float4*)(p + 1 * KDIM * H2);
                    float4 v2 = *(const float4*)(p + 2 * KDIM * H2);
                    float4 v3 = *(const float4*)(p + 3 * KDIM * H2);
                    float4 v4 = *(const float4*)(p + 4 * KDIM * H2);
                    float4 v = make_float4(v0.x+v1.x+v2.x+v3.x+v4.x,
                                           v0.y+v1.y+v2.y+v3.y+v4.y,
                                           v0.z+v1.z+v2.z+v3.z+v4.z,
                                           v0.w+v1.w+v2.w+v3.w+v4.w);
                    *(float4*)&Bs[k * 64 + c4 * 4] = v;
                }
            }
            __syncthreads();
            #pragma unroll 8
            for (int kk = 0; kk < 48; ++kk) {
                float a = As[ty * 388 + kb + kk];
                const float4 bv = *(const float4*)&Bs[kk * 64 + tx * 4];
                acc[0] += a * bv.x; acc[1] += a * bv.y;
                acc[2] += a * bv.z; acc[3] += a * bv.w;
            }
        }
        if (tx < w4) {
            const float4 bb = *(const float4*)(b2 + o0 + tx * 4);
            int u = r * 16 + ty;
            *(float4*)(pre2 + u * H2 + o0 + tx * 4) =
                make_float4(acc[0] + bb.x, acc[1] + bb.y, acc[2] + bb.z, acc[3] + bb.w);
        }
    }
    gbar(4, flags, rel);

    // ---------------- S4: n3p[s] = relu(pre2) @ Wcat3 (K-split 5) ----------
    // grid: 60 = d(6) x ot(2) x s(5); tile 64x64, span 100 = 5x20
    if (bid < 60) {
        const int s = bid % 5, ot = (bid / 5) % 2, d = bid / 10;
        const float* Bsec = (d < 4) ? (We3 + (size_t)d * (H2 * H3))
                                    : ((d == 4) ? be3 : root3);
        const int o0 = ot * 64;
        const int w4 = ot ? 9 : 16;  // H3=100
        float* As = smem;            // 64 x 28
        float* Bs = smem + 64 * 28;  // 20 x 64
        float acc[4][4] = {};
        for (int it = 0; it < 5; ++it) {
            const int kb = s * 100 + it * 20;
            __syncthreads();
            for (int idx = tid; idx < 320; idx += NT) {
                int r = idx / 5, c4 = idx - r * 5;
                float4 v = relu4(*(const float4*)(pre2 + r * H2 + kb + c4 * 4));
                *(float4*)&As[r * 28 + c4 * 4] = v;
            }
            for (int idx = tid; idx < 320; idx += NT) {
                int k = idx >> 4, c4 = idx & 15;
                if (c4 < w4)
                    *(float4*)&Bs[k * 64 + c4 * 4] =
                        *(const float4*)(Bsec + (size_t)(kb + k) * H3 + o0 + c4 * 4);
            }
            __syncthreads();
            #pragma unroll
            for (int kk = 0; kk < 20; ++kk) {
                float a0 = As[(ty * 4 + 0) * 28 + kk];
                float a1 = As[(ty * 4 + 1) * 28 + kk];
                float a2 = As[(ty * 4 + 2) * 28 + kk];
                float a3 = As[(ty * 4 + 3) * 28 + kk];
                const float4 bv = *(const float4*)&Bs[kk * 64 + tx * 4];
                acc[0][0] += a0 * bv.x; acc[0][1] += a0 * bv.y; acc[0][2] += a0 * bv.z; acc[0][3] += a0 * bv.w;
                acc[1][0] += a1 * bv.x; acc[1][1] += a1 * bv.y; acc[1][2] += a1 * bv.z; acc[1][3] += a1 * bv.w;
                acc[2][0] += a2 * bv.x; acc[2][1] += a2 * bv.y; acc[2][2] += a2 * bv.z; acc[2][3] += a2 * bv.w;
                acc[3][0] += a3 * bv.x; acc[3][1] += a3 * bv.y; acc[3][2] += a3 * bv.z; acc[3][3] += a3 * bv.w;
            }
        }
        if (tx < w4) {
            float* dst = n3p + s * (KDIM * H3);
            #pragma unroll
            for (int i = 0; i < 4; ++i) {
                int u = ty * 4 + i;
                *(float4*)(dst + (u * 6 + d) * H3 + o0 + tx * 4) =
                    make_float4(acc[i][0], acc[i][1], acc[i][2], acc[i][3]);
            }
        }
    }
    gbar(5, flags, rel);

    // ---------------- S5: pre3 = b3 + Ahat @ sum_s n3p[s] ------------------
    // grid: 8 = ot(2) x r(4); rows 16 x cols 64, K=384 (8x48)
    if (bid < 8) {
        const int ot = bid >> 2, r = bid & 3;
        const int o0 = ot * 64;
        const int w4 = ot ? 9 : 16;
        float* As = smem;
        float* Bs = smem + 16 * 388;
        for (int idx = tid; idx < 16 * 96; idx += NT) {
            int rr = idx / 96, c4 = idx - rr * 96;
            *(float4*)&As[rr * 388 + c4 * 4] =
                *(const float4*)(Ahat + (r * 16 + rr) * KDIM + c4 * 4);
        }
        float acc[4] = {};
        for (int it = 0; it < 8; ++it) {
            const int kb = it * 48;
            __syncthreads();
            for (int idx = tid; idx < 48 * 16; idx += NT) {
                int k = idx >> 4, c4 = idx & 15;
                if (c4 < w4) {
                    const float* p = n3p + (kb + k) * H3 + o0 + c4 * 4;
                    float4 v0 = *(const float4*)(p);
                    float4 v1 = *(const float4*)(p + 1 * KDIM * H3);
                    float4 v2 = *(const float4*)(p + 2 * KDIM * H3);
                    float4 v3 = *(const float4*)(p + 3 * KDIM * H3);
                    float4 v4 = *(const float4*)(p + 4 * KDIM * H3);
                    float4 v = make_float4(v0.x+v1.x+v2.x+v3.x+v4.x,
                                           v0.y+v1.y+v2.y+v3.y+v4.y,
                                           v0.z+v1.z+v2.z+v3.z+v4.z,
                                           v0.w+v1.w+v2.w+v3.w+v4.w);
                    *(float4*)&Bs[k * 64 + c4 * 4] = v;
                }
            }
            __syncthreads();
            #pragma unroll 8
            for (int kk = 0; kk < 48; ++kk) {
                float a = As[ty * 388 + kb + kk];
                const float4 bv = *(const float4*)&Bs[kk * 64 + tx * 4];
                acc[0] += a * bv.x; acc[1] += a * bv.y;
                acc[2] += a * bv.z; acc[3] += a * bv.w;
            }
        }
        if (tx < w4) {
            const float4 bb = *(const float4*)(b3 + o0 + tx * 4);
            int u = r * 16 + ty;
            *(float4*)(pre3 + u * H3 + o0 + tx * 4) =
                make_float4(acc[0] + bb.x, acc[1] + bb.y, acc[2] + bb.z, acc[3] + bb.w);
        }
    }
    gbar(6, flags, rel);

    // ---------------- S6: g = segsum(relu(pre3)); f1 = relu(c1 + g@W1) -----
    // grid: 64 = gi(4) x jt(16)
    if (bid < 64) {
        const int gi = bid >> 4, jt = bid & 15;
        const int o0 = jt * 64;
        int* bsh  = (int*)smem;        // 64
        float* gs  = smem + 64;        // 100
        float* red = smem + 192;       // 256
        if (tid < NN) bsh[tid] = batch[tid];
        __syncthreads();
        if (tid < H3) {
            float acc = 0.f;
            #pragma unroll
            for (int v = 0; v < NN; ++v) {
                float h = pre3[v * H3 + tid];
                h = h > 0.f ? h : 0.f;
                acc += (bsh[v] == gi) ? h : 0.f;
            }
            gs[tid] = acc;
        }
        __syncthreads();
        const int jj = tid & 63, kq = tid >> 6;
        const int oc = min(o0 + jj, FF1 - 1);
        float p = 0.f;
        #pragma unroll
        for (int k = kq * 25; k < kq * 25 + 25; ++k)
            p += gs[k] * W1[k * FF1 + oc];
        red[kq * 64 + jj] = p;
        __syncthreads();
        if (tid < 64) {
            int o = o0 + tid;
            if (o < FF1) {
                float v = c1[o] + red[tid] + red[64 + tid] + red[128 + tid] + red[192 + tid];
                f1w[gi * FF1 + o] = v > 0.f ? v : 0.f;
            }
        }
    }
    gbar(7, flags, rel);

    // ---------------- S7: f2 += f1 @ W2 (K=1000 over 16 blocks, atomic) ----
    if (bid < 16) {
        const int k0 = bid * 63;
        const int kn = (k0 + 63 <= FF1) ? 63 : (FF1 - k0);
        float* f1s = smem;  // 4*63
        for (int i = tid; i < GG * kn; i += NT) {
            int g = i / kn, kk = i - g * kn;
            f1s[g * 63 + kk] = f1w[g * FF1 + k0 + kk];
        }
        __syncthreads();
        for (int idx = tid; idx < GG * FF2; idx += NT) {
            int g = idx / FF2, o = idx - g * FF2;
            float acc = 0.f;
            for (int kk = 0; kk < kn; ++kk)
                acc += f1s[g * 63 + kk] * W2[(k0 + kk) * FF2 + o];
            atomicAdd(&f2w[idx], acc);
        }
    }
    gbar(8, flags, rel);

    // ---------------- S8: f3 = relu(relu(f2)@W3 + c3); out = f3@W4 + c4 ----
    if (bid == 0) {
        float* f2s = smem;        // 400
        float* f3s = smem + 400;  // 200
        for (int i = tid; i < GG * FF2; i += NT) {
            float v = f2w[i];
            f2s[i] = v > 0.f ? v : 0.f;
        }
        __syncthreads();
        if (tid < GG * FF3) {
            int g = tid / FF3, o = tid - g * FF3;
            float acc = c3[o];
            for (int k = 0; k < FF2; ++k)
                acc += f2s[g * FF2 + k] * W3[k * FF3 + o];
            f3s[tid] = acc > 0.f ? acc : 0.f;
        }
        __syncthreads();
        if (tid < GG) {
            float acc = c4[0];
            #pragma unroll
            for (int k = 0; k < FF3; ++k) acc += f3s[tid * FF3 + k] * W4[k];
            out[tid] = acc;
        }
    }
}

extern "C" void kernel_launch(void* const* d_in, const int* in_sizes, int n_in,
                              void* d_out, int out_size, void* d_ws, size_t ws_size,
                              hipStream_t stream) {
    const float* x          = (const float*)d_in[0];
    const int*   edge_index = (const int*)  d_in[1];
    const float* edge_attr  = (const float*)d_in[2];
    const int*   batch      = (const int*)  d_in[3];
    const float* We1 = (const float*)d_in[4];
    const float* be1 = (const float*)d_in[5];
    const float* root1 = (const float*)d_in[6];
    const float* b1  = (const float*)d_in[7];
    const float* We2 = (const float*)d_in[8];
    const float* be2 = (const float*)d_in[9];
    const float* root2 = (const float*)d_in[10];
    const float* b2  = (const float*)d_in[11];
    const float* We3 = (const float*)d_in[12];
    const float* be3 = (const float*)d_in[13];
    const float* root3 = (const float*)d_in[14];
    const float* b3  = (const float*)d_in[15];
    const float* W1 = (const float*)d_in[16];
    const float* c1 = (const float*)d_in[17];
    const float* W2 = (const float*)d_in[18];
    const float* c2 = (const float*)d_in[19];
    const float* W3 = (const float*)d_in[20];
    const float* c3 = (const float*)d_in[21];
    const float* W4 = (const float*)d_in[22];
    const float* c4 = (const float*)d_in[23];

    fused_gnn<<<GRID, NT, 0, stream>>>(
        x, edge_index, edge_attr, batch,
        We1, be1, root1, b1, We2, be2, root2, b2, We3, be3, root3, b3,
        W1, c1, W2, c2, W3, c3, W4, c4,
        (float*)d_ws, (float*)d_out);
}

// Round 5
// 337.273 us; speedup vs baseline: 1.9499x; 1.9499x over previous
//
#include <hip/hip_runtime.h>

// ---------------------------------------------------------------------------
// Single fused persistent kernel: 256 blocks x 256 threads (1 block/CU),
// manual grid barriers (init-free, works for any initial ws contents).
// R5 fix: barrier spins with RELAXED atomic loads + s_sleep backoff and a
// single acquire fence on exit. R4 spun with ACQUIRE loads, whose per-
// iteration cache invalidations (from ~224 idle blocks) wiped the XCD L2s
// under the working blocks every stage -> 578 us at 1.4% VALUBusy.
// ---------------------------------------------------------------------------

#define GRID 256
#define NT   256

// dims
#define NN 64
#define EE 128
#define GG 4
#define D0 9
#define H1 2000
#define H2 500
#define H3 100
#define FF1 1000
#define FF2 100
#define FF3 50
#define KDIM 384  // 64 nodes * 6 channels (4 edge-attr + 1 bias-row + 1 root)

// ws layout (float indices). ws[0..255]=flags, ws[256]=release word.
#define OFF_A    272       // 64*384   = 24576
#define OFF_Y    24848     // 64*54    = 3456
#define OFF_PRE1 28304     // 64*2000  = 128000 (raw pre-activation, b1 added)
#define OFF_N2P  156304    // 5 * 384*500 = 960000 (K-split partials)
#define OFF_PRE2 1116304   // 64*500   = 32000 (raw, b2 added)
#define OFF_N3P  1148304   // 5 * 384*100 = 192000
#define OFF_PRE3 1340304   // 64*100   = 6400 (raw, b3 added)
#define OFF_F1   1346704   // 4*1000 (post-relu)
#define OFF_F2   1350704   // 4*100  (c2 preloaded + atomic partial adds)
// total 1,351,104 floats = 5.40 MB

__device__ __forceinline__ float4 relu4(float4 v) {
    v.x = v.x > 0.f ? v.x : 0.f; v.y = v.y > 0.f ? v.y : 0.f;
    v.z = v.z > 0.f ? v.z : 0.f; v.w = v.w > 0.f ? v.w : 0.f;
    return v;
}

// Init-free grid barrier. Spin RELAXED (no cache-invalidate side effects),
// one acquire fence after the observed flag; release semantics on the flag
// stores publish each block's data. Phases 1..8 never collide with the
// 0xAAAAAAAA poison the harness writes into ws before every launch.
__device__ __forceinline__ void gbar(unsigned phase, unsigned* flags,
                                     unsigned* rel) {
    __syncthreads();
    if (blockIdx.x == 0) {
        if (threadIdx.x < 64) {
            for (int j = 1 + (int)threadIdx.x; j < GRID; j += 64) {
                while (__hip_atomic_load(&flags[j], __ATOMIC_RELAXED,
                                         __HIP_MEMORY_SCOPE_AGENT) != phase)
                    __builtin_amdgcn_s_sleep(8);
            }
        }
        __syncthreads();
        if (threadIdx.x == 0) {
            // acquire all blocks' released writes, then publish transitively
            __builtin_amdgcn_fence(__ATOMIC_ACQUIRE, "agent");
            __hip_atomic_store(rel, phase, __ATOMIC_RELEASE,
                               __HIP_MEMORY_SCOPE_AGENT);
        }
        __syncthreads();
        __builtin_amdgcn_fence(__ATOMIC_ACQUIRE, "agent");
    } else {
        if (threadIdx.x == 0) {
            __hip_atomic_store(&flags[blockIdx.x], phase, __ATOMIC_RELEASE,
                               __HIP_MEMORY_SCOPE_AGENT);
            while (__hip_atomic_load(rel, __ATOMIC_RELAXED,
                                     __HIP_MEMORY_SCOPE_AGENT) != phase)
                __builtin_amdgcn_s_sleep(16);
        }
        __syncthreads();
        __builtin_amdgcn_fence(__ATOMIC_ACQUIRE, "agent");
    }
}

__global__ __launch_bounds__(NT, 2) void fused_gnn(
    const float* __restrict__ x, const int* __restrict__ edge_index,
    const float* __restrict__ edge_attr, const int* __restrict__ batch,
    const float* __restrict__ We1, const float* __restrict__ be1,
    const float* __restrict__ root1, const float* __restrict__ b1,
    const float* __restrict__ We2, const float* __restrict__ be2,
    const float* __restrict__ root2, const float* __restrict__ b2,
    const float* __restrict__ We3, const float* __restrict__ be3,
    const float* __restrict__ root3, const float* __restrict__ b3,
    const float* __restrict__ W1, const float* __restrict__ c1,
    const float* __restrict__ W2, const float* __restrict__ c2,
    const float* __restrict__ W3, const float* __restrict__ c3,
    const float* __restrict__ W4, const float* __restrict__ c4,
    float* __restrict__ ws, float* __restrict__ out)
{
    __shared__ float smem[9600];  // 38.4 KB union; 1+ block/CU guaranteed

    unsigned* flags = (unsigned*)ws;
    unsigned* rel   = flags + GRID;
    const int bid = blockIdx.x, tid = threadIdx.x;
    const int tx = tid & 15, ty = tid >> 4;

    float* Ahat = ws + OFF_A;
    float* Yw   = ws + OFF_Y;
    float* pre1 = ws + OFF_PRE1;
    float* n2p  = ws + OFF_N2P;
    float* pre2 = ws + OFF_PRE2;
    float* n3p  = ws + OFF_N3P;
    float* pre3 = ws + OFF_PRE3;
    float* f1w  = ws + OFF_F1;
    float* f2w  = ws + OFF_F2;

    // ---------------- S0: A-hat, Y, f2 preload ----------------
    if (bid == 0) {
        for (int i = tid; i < NN * KDIM; i += NT) Ahat[i] = 0.f;
        __syncthreads();
        if (tid < EE) {
            int s = edge_index[tid], t = edge_index[EE + tid];
            float* row = Ahat + t * KDIM + s * 6;
            #pragma unroll
            for (int d = 0; d < 4; ++d) atomicAdd(row + d, edge_attr[tid * 4 + d]);
            atomicAdd(row + 4, 1.0f);
        }
        if (tid < NN) Ahat[tid * KDIM + tid * 6 + 5] = 1.0f;
    } else if (bid == 1) {
        float* Ys = smem;  // 64*54
        for (int i = tid; i < NN * 54; i += NT) Ys[i] = 0.f;
        __syncthreads();
        if (tid < EE) {
            int s = edge_index[tid], t = edge_index[EE + tid];
            float ea[4];
            #pragma unroll
            for (int d = 0; d < 4; ++d) ea[d] = edge_attr[tid * 4 + d];
            #pragma unroll
            for (int i = 0; i < D0; ++i) {
                float xv = x[s * D0 + i];
                #pragma unroll
                for (int d = 0; d < 4; ++d)
                    atomicAdd(&Ys[t * 54 + d * 9 + i], ea[d] * xv);
                atomicAdd(&Ys[t * 54 + 36 + i], xv);
            }
        }
        if (tid < NN) {
            #pragma unroll
            for (int i = 0; i < D0; ++i) Ys[tid * 54 + 45 + i] = x[tid * D0 + i];
        }
        __syncthreads();
        for (int i = tid; i < NN * 54; i += NT) Yw[i] = Ys[i];
    } else if (bid == 2) {
        for (int i = tid; i < GG * FF2; i += NT) f2w[i] = c2[i % FF2];
    }
    gbar(1, flags, rel);

    // ---------------- S1: pre1 = b1 + Y @ Wcat1 [64x54]@[54x2000] ----------
    if (bid < 32) {
        float* Ys = smem;           // 64*57 padded
        float* Bs = smem + 64 * 57; // 54*64
        const int o0 = bid * 64;
        const int w = (o0 + 64 <= H1) ? 64 : (H1 - o0);
        for (int i = tid; i < NN * 54; i += NT) {
            int u = i / 54, r = i - u * 54;
            Ys[u * 57 + r] = Yw[i];
        }
        for (int i = tid; i < 54 * 64; i += NT) {
            int r = i >> 6, c = i & 63;
            int d = r / 9, ii = r - d * 9;
            const float* rowp = ((d < 4) ? (We1 + d * (D0 * H1))
                                         : ((d == 4) ? be1 : root1)) + ii * H1;
            Bs[r * 64 + c] = (c < w) ? rowp[o0 + c] : 0.f;
        }
        __syncthreads();
        float acc[4][4] = {};
        #pragma unroll 6
        for (int r = 0; r < 54; ++r) {
            float a0 = Ys[(ty * 4 + 0) * 57 + r];
            float a1 = Ys[(ty * 4 + 1) * 57 + r];
            float a2 = Ys[(ty * 4 + 2) * 57 + r];
            float a3 = Ys[(ty * 4 + 3) * 57 + r];
            const float4 bv = *(const float4*)&Bs[r * 64 + tx * 4];
            acc[0][0] += a0 * bv.x; acc[0][1] += a0 * bv.y; acc[0][2] += a0 * bv.z; acc[0][3] += a0 * bv.w;
            acc[1][0] += a1 * bv.x; acc[1][1] += a1 * bv.y; acc[1][2] += a1 * bv.z; acc[1][3] += a1 * bv.w;
            acc[2][0] += a2 * bv.x; acc[2][1] += a2 * bv.y; acc[2][2] += a2 * bv.z; acc[2][3] += a2 * bv.w;
            acc[3][0] += a3 * bv.x; acc[3][1] += a3 * bv.y; acc[3][2] += a3 * bv.z; acc[3][3] += a3 * bv.w;
        }
        if (tx * 4 < w) {
            const float4 bb = *(const float4*)(b1 + o0 + tx * 4);
            #pragma unroll
            for (int i = 0; i < 4; ++i) {
                int u = ty * 4 + i;
                float4 v = make_float4(acc[i][0] + bb.x, acc[i][1] + bb.y,
                                       acc[i][2] + bb.z, acc[i][3] + bb.w);
                *(float4*)(pre1 + u * H1 + o0 + tx * 4) = v;
            }
        }
    }
    gbar(2, flags, rel);

    // ---------------- S2: n2p[s] = relu(pre1) @ Wcat2 (K-split 5) ----------
    // grid: 240 blocks = d(6) x ot(8) x s(5); tile 64x64, span 400 = 10x40
    if (bid < 240) {
        const int s = bid % 5, ot = (bid / 5) % 8, d = bid / 40;
        const float* Bsec = (d < 4) ? (We2 + (size_t)d * (H1 * H2))
                                    : ((d == 4) ? be2 : root2);
        const int o0 = ot * 64;
        const int w4 = (o0 + 64 <= H2) ? 16 : ((H2 - o0) >> 2);  // ot7: 13
        float* As = smem;            // 64 x 44
        float* Bs = smem + 64 * 44;  // 40 x 64
        float acc[4][4] = {};
        for (int it = 0; it < 10; ++it) {
            const int kb = s * 400 + it * 40;
            __syncthreads();
            for (int idx = tid; idx < 640; idx += NT) {
                int r = idx / 10, c4 = idx - r * 10;
                float4 v = relu4(*(const float4*)(pre1 + r * H1 + kb + c4 * 4));
                *(float4*)&As[r * 44 + c4 * 4] = v;
            }
            for (int idx = tid; idx < 640; idx += NT) {
                int k = idx >> 4, c4 = idx & 15;
                if (c4 < w4)
                    *(float4*)&Bs[k * 64 + c4 * 4] =
                        *(const float4*)(Bsec + (size_t)(kb + k) * H2 + o0 + c4 * 4);
            }
            __syncthreads();
            #pragma unroll 8
            for (int kk = 0; kk < 40; ++kk) {
                float a0 = As[(ty * 4 + 0) * 44 + kk];
                float a1 = As[(ty * 4 + 1) * 44 + kk];
                float a2 = As[(ty * 4 + 2) * 44 + kk];
                float a3 = As[(ty * 4 + 3) * 44 + kk];
                const float4 bv = *(const float4*)&Bs[kk * 64 + tx * 4];
                acc[0][0] += a0 * bv.x; acc[0][1] += a0 * bv.y; acc[0][2] += a0 * bv.z; acc[0][3] += a0 * bv.w;
                acc[1][0] += a1 * bv.x; acc[1][1] += a1 * bv.y; acc[1][2] += a1 * bv.z; acc[1][3] += a1 * bv.w;
                acc[2][0] += a2 * bv.x; acc[2][1] += a2 * bv.y; acc[2][2] += a2 * bv.z; acc[2][3] += a2 * bv.w;
                acc[3][0] += a3 * bv.x; acc[3][1] += a3 * bv.y; acc[3][2] += a3 * bv.z; acc[3][3] += a3 * bv.w;
            }
        }
        if (tx < w4) {
            float* dst = n2p + s * (KDIM * H2);
            #pragma unroll
            for (int i = 0; i < 4; ++i) {
                int u = ty * 4 + i;
                *(float4*)(dst + (u * 6 + d) * H2 + o0 + tx * 4) =
                    make_float4(acc[i][0], acc[i][1], acc[i][2], acc[i][3]);
            }
        }
    }
    gbar(3, flags, rel);

    // ---------------- S3: pre2 = b2 + Ahat @ sum_s n2p[s] ------------------
    // grid: 32 = ot(8) x r(4); block = rows 16 x cols 64, K=384 (8x48)
    if (bid < 32) {
        const int ot = bid >> 2, r = bid & 3;
        const int o0 = ot * 64;
        const int w4 = (o0 + 64 <= H2) ? 16 : ((H2 - o0) >> 2);
        float* As = smem;             // 16 x 388
        float* Bs = smem + 16 * 388;  // 48 x 64
        for (int idx = tid; idx < 16 * 96; idx += NT) {
            int rr = idx / 96, c4 = idx - rr * 96;
            *(float4*)&As[rr * 388 + c4 * 4] =
                *(const float4*)(Ahat + (r * 16 + rr) * KDIM + c4 * 4);
        }
        float acc[4] = {};
        for (int it = 0; it < 8; ++it) {
            const int kb = it * 48;
            __syncthreads();
            for (int idx = tid; idx < 48 * 16; idx += NT) {
                int k = idx >> 4, c4 = idx & 15;
                if (c4 < w4) {
                    const float* p = n2p + (kb + k) * H2 + o0 + c4 * 4;
                    float4 v0 = *(const float4*)(p);
                    float4 v1 = *(const float4*)(p + 1 * KDIM * H2);
                    float4 v2 = *(const float4*)(p + 2 * KDIM * H2);
                    float4 v3 = *(const float4*)(p + 3 * KDIM * H2);
                    float4 v4 = *(const float4*)(p + 4 * KDIM * H2);
                    float4 v = make_float4(v0.x+v1.x+v2.x+v3.x+v4.x,
                                           v0.y+v1.y+v2.y+v3.y+v4.y,
                                           v0.z+v1.z+v2.z+v3.z+v4.z,
                                           v0.w+v1.w+v2.w+v3.w+v4.w);
                    *(float4*)&Bs[k * 64 + c4 * 4] = v;
                }
            }
            __syncthreads();
            #pragma unroll 8
            for (int kk = 0; kk < 48; ++kk) {
                float a = As[ty * 388 + kb + kk];
                const float4 bv = *(const float4*)&Bs[kk * 64 + tx * 4];
                acc[0] += a * bv.x; acc[1] += a * bv.y;
                acc[2] += a * bv.z; acc[3] += a * bv.w;
            }
        }
        if (tx < w4) {
            const float4 bb = *(const float4*)(b2 + o0 + tx * 4);
            int u = r * 16 + ty;
            *(float4*)(pre2 + u * H2 + o0 + tx * 4) =
                make_float4(acc[0] + bb.x, acc[1] + bb.y, acc[2] + bb.z, acc[3] + bb.w);
        }
    }
    gbar(4, flags, rel);

    // ---------------- S4: n3p[s] = relu(pre2) @ Wcat3 (K-split 5) ----------
    // grid: 60 = d(6) x ot(2) x s(5); tile 64x64, span 100 = 5x20
    if (bid < 60) {
        const int s = bid % 5, ot = (bid / 5) % 2, d = bid / 10;
        const float* Bsec = (d < 4) ? (We3 + (size_t)d * (H2 * H3))
                                    : ((d == 4) ? be3 : root3);
        const int o0 = ot * 64;
        const int w4 = ot ? 9 : 16;  // H3=100
        float* As = smem;            // 64 x 28
        float* Bs = smem + 64 * 28;  // 20 x 64
        float acc[4][4] = {};
        for (int it = 0; it < 5; ++it) {
            const int kb = s * 100 + it * 20;
            __syncthreads();
            for (int idx = tid; idx < 320; idx += NT) {
                int r = idx / 5, c4 = idx - r * 5;
                float4 v = relu4(*(const float4*)(pre2 + r * H2 + kb + c4 * 4));
                *(float4*)&As[r * 28 + c4 * 4] = v;
            }
            for (int idx = tid; idx < 320; idx += NT) {
                int k = idx >> 4, c4 = idx & 15;
                if (c4 < w4)
                    *(float4*)&Bs[k * 64 + c4 * 4] =
                        *(const float4*)(Bsec + (size_t)(kb + k) * H3 + o0 + c4 * 4);
            }
            __syncthreads();
            #pragma unroll
            for (int kk = 0; kk < 20; ++kk) {
                float a0 = As[(ty * 4 + 0) * 28 + kk];
                float a1 = As[(ty * 4 + 1) * 28 + kk];
                float a2 = As[(ty * 4 + 2) * 28 + kk];
                float a3 = As[(ty * 4 + 3) * 28 + kk];
                const float4 bv = *(const float4*)&Bs[kk * 64 + tx * 4];
                acc[0][0] += a0 * bv.x; acc[0][1] += a0 * bv.y; acc[0][2] += a0 * bv.z; acc[0][3] += a0 * bv.w;
                acc[1][0] += a1 * bv.x; acc[1][1] += a1 * bv.y; acc[1][2] += a1 * bv.z; acc[1][3] += a1 * bv.w;
                acc[2][0] += a2 * bv.x; acc[2][1] += a2 * bv.y; acc[2][2] += a2 * bv.z; acc[2][3] += a2 * bv.w;
                acc[3][0] += a3 * bv.x; acc[3][1] += a3 * bv.y; acc[3][2] += a3 * bv.z; acc[3][3] += a3 * bv.w;
            }
        }
        if (tx < w4) {
            float* dst = n3p + s * (KDIM * H3);
            #pragma unroll
            for (int i = 0; i < 4; ++i) {
                int u = ty * 4 + i;
                *(float4*)(dst + (u * 6 + d) * H3 + o0 + tx * 4) =
                    make_float4(acc[i][0], acc[i][1], acc[i][2], acc[i][3]);
            }
        }
    }
    gbar(5, flags, rel);

    // ---------------- S5: pre3 = b3 + Ahat @ sum_s n3p[s] ------------------
    // grid: 8 = ot(2) x r(4); rows 16 x cols 64, K=384 (8x48)
    if (bid < 8) {
        const int ot = bid >> 2, r = bid & 3;
        const int o0 = ot * 64;
        const int w4 = ot ? 9 : 16;
        float* As = smem;
        float* Bs = smem + 16 * 388;
        for (int idx = tid; idx < 16 * 96; idx += NT) {
            int rr = idx / 96, c4 = idx - rr * 96;
            *(float4*)&As[rr * 388 + c4 * 4] =
                *(const float4*)(Ahat + (r * 16 + rr) * KDIM + c4 * 4);
        }
        float acc[4] = {};
        for (int it = 0; it < 8; ++it) {
            const int kb = it * 48;
            __syncthreads();
            for (int idx = tid; idx < 48 * 16; idx += NT) {
                int k = idx >> 4, c4 = idx & 15;
                if (c4 < w4) {
                    const float* p = n3p + (kb + k) * H3 + o0 + c4 * 4;
                    float4 v0 = *(const float4*)(p);
                    float4 v1 = *(const float4*)(p + 1 * KDIM * H3);
                    float4 v2 = *(const float4*)(p + 2 * KDIM * H3);
                    float4 v3 = *(const float4*)(p + 3 * KDIM * H3);
                    float4 v4 = *(const float4*)(p + 4 * KDIM * H3);
                    float4 v = make_float4(v0.x+v1.x+v2.x+v3.x+v4.x,
                                           v0.y+v1.y+v2.y+v3.y+v4.y,
                                           v0.z+v1.z+v2.z+v3.z+v4.z,
                                           v0.w+v1.w+v2.w+v3.w+v4.w);
                    *(float4*)&Bs[k * 64 + c4 * 4] = v;
                }
            }
            __syncthreads();
            #pragma unroll 8
            for (int kk = 0; kk < 48; ++kk) {
                float a = As[ty * 388 + kb + kk];
                const float4 bv = *(const float4*)&Bs[kk * 64 + tx * 4];
                acc[0] += a * bv.x; acc[1] += a * bv.y;
                acc[2] += a * bv.z; acc[3] += a * bv.w;
            }
        }
        if (tx < w4) {
            const float4 bb = *(const float4*)(b3 + o0 + tx * 4);
            int u = r * 16 + ty;
            *(float4*)(pre3 + u * H3 + o0 + tx * 4) =
                make_float4(acc[0] + bb.x, acc[1] + bb.y, acc[2] + bb.z, acc[3] + bb.w);
        }
    }
    gbar(6, flags, rel);

    // ---------------- S6: g = segsum(relu(pre3)); f1 = relu(c1 + g@W1) -----
    // grid: 64 = gi(4) x jt(16)
    if (bid < 64) {
        const int gi = bid >> 4, jt = bid & 15;
        const int o0 = jt * 64;
        int* bsh  = (int*)smem;        // 64
        float* gs  = smem + 64;        // 100
        float* red = smem + 192;       // 256
        if (tid < NN) bsh[tid] = batch[tid];
        __syncthreads();
        if (tid < H3) {
            float acc = 0.f;
            #pragma unroll
            for (int v = 0; v < NN; ++v) {
                float h = pre3[v * H3 + tid];
                h = h > 0.f ? h : 0.f;
                acc += (bsh[v] == gi) ? h : 0.f;
            }
            gs[tid] = acc;
        }
        __syncthreads();
        const int jj = tid & 63, kq = tid >> 6;
        const int oc = min(o0 + jj, FF1 - 1);
        float p = 0.f;
        #pragma unroll
        for (int k = kq * 25; k < kq * 25 + 25; ++k)
            p += gs[k] * W1[k * FF1 + oc];
        red[kq * 64 + jj] = p;
        __syncthreads();
        if (tid < 64) {
            int o = o0 + tid;
            if (o < FF1) {
                float v = c1[o] + red[tid] + red[64 + tid] + red[128 + tid] + red[192 + tid];
                f1w[gi * FF1 + o] = v > 0.f ? v : 0.f;
            }
        }
    }
    gbar(7, flags, rel);

    // ---------------- S7: f2 += f1 @ W2 (K=1000 over 16 blocks, atomic) ----
    if (bid < 16) {
        const int k0 = bid * 63;
        const int kn = (k0 + 63 <= FF1) ? 63 : (FF1 - k0);
        float* f1s = smem;  // 4*63
        for (int i = tid; i < GG * kn; i += NT) {
            int g = i / kn, kk = i - g * kn;
            f1s[g * 63 + kk] = f1w[g * FF1 + k0 + kk];
        }
        __syncthreads();
        for (int idx = tid; idx < GG * FF2; idx += NT) {
            int g = idx / FF2, o = idx - g * FF2;
            float acc = 0.f;
            for (int kk = 0; kk < kn; ++kk)
                acc += f1s[g * 63 + kk] * W2[(k0 + kk) * FF2 + o];
            atomicAdd(&f2w[idx], acc);
        }
    }
    gbar(8, flags, rel);

    // ---------------- S8: f3 = relu(relu(f2)@W3 + c3); out = f3@W4 + c4 ----
    if (bid == 0) {
        float* f2s = smem;        // 400
        float* f3s = smem + 400;  // 200
        for (int i = tid; i < GG * FF2; i += NT) {
            float v = f2w[i];
            f2s[i] = v > 0.f ? v : 0.f;
        }
        __syncthreads();
        if (tid < GG * FF3) {
            int g = tid / FF3, o = tid - g * FF3;
            float acc = c3[o];
            for (int k = 0; k < FF2; ++k)
                acc += f2s[g * FF2 + k] * W3[k * FF3 + o];
            f3s[tid] = acc > 0.f ? acc : 0.f;
        }
        __syncthreads();
        if (tid < GG) {
            float acc = c4[0];
            #pragma unroll
            for (int k = 0; k < FF3; ++k) acc += f3s[tid * FF3 + k] * W4[k];
            out[tid] = acc;
        }
    }
}

extern "C" void kernel_launch(void* const* d_in, const int* in_sizes, int n_in,
                              void* d_out, int out_size, void* d_ws, size_t ws_size,
                              hipStream_t stream) {
    const float* x          = (const float*)d_in[0];
    const int*   edge_index = (const int*)  d_in[1];
    const float* edge_attr  = (const float*)d_in[2];
    const int*   batch      = (const int*)  d_in[3];
    const float* We1 = (const float*)d_in[4];
    const float* be1 = (const float*)d_in[5];
    const float* root1 = (const float*)d_in[6];
    const float* b1  = (const float*)d_in[7];
    const float* We2 = (const float*)d_in[8];
    const float* be2 = (const float*)d_in[9];
    const float* root2 = (const float*)d_in[10];
    const float* b2  = (const float*)d_in[11];
    const float* We3 = (const float*)d_in[12];
    const float* be3 = (const float*)d_in[13];
    const float* root3 = (const float*)d_in[14];
    const float* b3  = (const float*)d_in[15];
    const float* W1 = (const float*)d_in[16];
    const float* c1 = (const float*)d_in[17];
    const float* W2 = (const float*)d_in[18];
    const float* c2 = (const float*)d_in[19];
    const float* W3 = (const float*)d_in[20];
    const float* c3 = (const float*)d_in[21];
    const float* W4 = (const float*)d_in[22];
    const float* c4 = (const float*)d_in[23];

    fused_gnn<<<GRID, NT, 0, stream>>>(
        x, edge_index, edge_attr, batch,
        We1, be1, root1, b1, We2, be2, root2, b2, We3, be3, root3, b3,
        W1, c1, W2, c2, W3, c3, W4, c4,
        (float*)d_ws, (float*)d_out);
}

// Round 6
// 265.307 us; speedup vs baseline: 2.4788x; 1.2713x over previous
//
#include <hip/hip_runtime.h>

// ---------------------------------------------------------------------------
// Fused persistent kernel, 512 blocks x 256 threads (2 blocks/CU, 8 waves/CU).
// Block 0 = barrier master (no stage work). Role-based grid barrier: only
// producers pay the release (L2 writeback), only consumers pay the acquire
// (cache invalidate); idle blocks arrive relaxed. All stages atomics-free
// (K-split partials + dedicated streaming sum stage).
// ---------------------------------------------------------------------------

#define GRID 512
#define NT   256

// dims
#define NN 64
#define EE 128
#define GG 4
#define D0 9
#define H1 2000
#define H2 500
#define H3 100
#define FF1 1000
#define FF2 100
#define FF3 50
#define KDIM 384  // 64 nodes * 6 channels

// ws layout (float indices). ws[0..511]=flags, ws[512]=release word.
#define OFF_A    528        // 64*384    = 24576   A-hat
#define OFF_PRE1 25104      // 64*2000   = 128000  (b1 added, raw preact)
#define OFF_N2P  153104     // 10*384*500= 1920000 (S2 K-split partials)
#define OFF_N2   2073104    // 384*500   = 192000  (summed)
#define OFF_PRE2 2265104    // 64*500    = 32000   (b2 added, raw)
#define OFF_N3P  2297104    // 5*384*100 = 192000  (S4 K-split partials)
#define OFF_G    2489104    // 4*100     = 400     (per-graph readout)
#define OFF_F2P  2489504    // 16*400    = 6400    (H1 partials)
// total 2,495,904 floats = 9.98 MB

__device__ __forceinline__ float4 relu4(float4 v) {
    v.x = v.x > 0.f ? v.x : 0.f; v.y = v.y > 0.f ? v.y : 0.f;
    v.z = v.z > 0.f ? v.z : 0.f; v.w = v.w > 0.f ? v.w : 0.f;
    return v;
}

// Role-based init-free grid barrier. Phases 1..7 never collide with the
// 0xAAAAAAAA poison. Master (block 0) ignores the role flags.
__device__ __forceinline__ void gbar(unsigned phase, unsigned* flags,
                                     unsigned* rel, bool produced,
                                     bool consume) {
    __syncthreads();
    if (blockIdx.x == 0) {
        for (int j = 1 + (int)threadIdx.x; j < GRID; j += NT) {
            while (__hip_atomic_load(&flags[j], __ATOMIC_RELAXED,
                                     __HIP_MEMORY_SCOPE_AGENT) != phase)
                __builtin_amdgcn_s_sleep(1);
        }
        __syncthreads();
        if (threadIdx.x == 0) {
            __builtin_amdgcn_fence(__ATOMIC_ACQUIRE, "agent");
            __hip_atomic_store(rel, phase, __ATOMIC_RELEASE,
                               __HIP_MEMORY_SCOPE_AGENT);
        }
        __syncthreads();
    } else {
        if (threadIdx.x == 0) {
            if (produced)
                __builtin_amdgcn_fence(__ATOMIC_RELEASE, "agent");
            __hip_atomic_store(&flags[blockIdx.x], phase, __ATOMIC_RELAXED,
                               __HIP_MEMORY_SCOPE_AGENT);
            while (__hip_atomic_load(rel, __ATOMIC_RELAXED,
                                     __HIP_MEMORY_SCOPE_AGENT) != phase)
                __builtin_amdgcn_s_sleep(8);
        }
        __syncthreads();
        if (consume)
            __builtin_amdgcn_fence(__ATOMIC_ACQUIRE, "agent");
    }
}

__global__ __launch_bounds__(NT, 2) void fused_gnn(
    const float* __restrict__ x, const int* __restrict__ edge_index,
    const float* __restrict__ edge_attr, const int* __restrict__ batch,
    const float* __restrict__ We1, const float* __restrict__ be1,
    const float* __restrict__ root1, const float* __restrict__ b1,
    const float* __restrict__ We2, const float* __restrict__ be2,
    const float* __restrict__ root2, const float* __restrict__ b2,
    const float* __restrict__ We3, const float* __restrict__ be3,
    const float* __restrict__ root3, const float* __restrict__ b3,
    const float* __restrict__ W1, const float* __restrict__ c1,
    const float* __restrict__ W2, const float* __restrict__ c2,
    const float* __restrict__ W3, const float* __restrict__ c3,
    const float* __restrict__ W4, const float* __restrict__ c4,
    float* __restrict__ ws, float* __restrict__ out)
{
    __shared__ float smem[9600];  // 38.4 KB; 2 blocks/CU fits easily

    unsigned* flags = (unsigned*)ws;
    unsigned* rel   = flags + GRID;
    const int bid = blockIdx.x, tid = threadIdx.x;
    const int wid = bid - 1;               // worker id; bid 0 = master
    const int tx = tid & 15, ty = tid >> 4;

    float* Ahat = ws + OFF_A;
    float* pre1 = ws + OFF_PRE1;
    float* n2p  = ws + OFF_N2P;
    float* n2   = ws + OFF_N2;
    float* pre2 = ws + OFF_PRE2;
    float* n3p  = ws + OFF_N3P;
    float* gw   = ws + OFF_G;
    float* f2p  = ws + OFF_F2P;

    // ========== T0: S1 (32 blocks, Y built in LDS) + Ahat (1 block) ========
    if (wid >= 0 && wid < 32) {
        float* Ys = smem;            // 64*57 = 3648 (padded, built by scatter)
        float* Bs = smem + 3648;     // 54*64 = 3456
        for (int i = tid; i < 64 * 57; i += NT) Ys[i] = 0.f;
        __syncthreads();
        if (tid < EE) {
            int s = edge_index[tid], t = edge_index[EE + tid];
            float ea0 = edge_attr[tid * 4 + 0], ea1 = edge_attr[tid * 4 + 1];
            float ea2 = edge_attr[tid * 4 + 2], ea3 = edge_attr[tid * 4 + 3];
            #pragma unroll
            for (int i = 0; i < D0; ++i) {
                float xv = x[s * D0 + i];
                atomicAdd(&Ys[t * 57 + i],      ea0 * xv);
                atomicAdd(&Ys[t * 57 + 9 + i],  ea1 * xv);
                atomicAdd(&Ys[t * 57 + 18 + i], ea2 * xv);
                atomicAdd(&Ys[t * 57 + 27 + i], ea3 * xv);
                atomicAdd(&Ys[t * 57 + 36 + i], xv);
            }
        }
        if (tid < NN) {
            #pragma unroll
            for (int i = 0; i < D0; ++i)
                Ys[tid * 57 + 45 + i] = x[tid * D0 + i];
        }
        const int o0 = wid * 64;
        const int w = (o0 + 64 <= H1) ? 64 : (H1 - o0);
        for (int i = tid; i < 54 * 64; i += NT) {
            int r = i >> 6, c = i & 63;
            int d = r / 9, ii = r - d * 9;
            const float* rowp = ((d < 4) ? (We1 + d * (D0 * H1))
                                         : ((d == 4) ? be1 : root1)) + ii * H1;
            Bs[r * 64 + c] = (c < w) ? rowp[o0 + c] : 0.f;
        }
        __syncthreads();
        float acc[4][4] = {};
        #pragma unroll 6
        for (int r = 0; r < 54; ++r) {
            float a0 = Ys[(ty * 4 + 0) * 57 + r];
            float a1 = Ys[(ty * 4 + 1) * 57 + r];
            float a2 = Ys[(ty * 4 + 2) * 57 + r];
            float a3 = Ys[(ty * 4 + 3) * 57 + r];
            const float4 bv = *(const float4*)&Bs[r * 64 + tx * 4];
            acc[0][0] += a0 * bv.x; acc[0][1] += a0 * bv.y; acc[0][2] += a0 * bv.z; acc[0][3] += a0 * bv.w;
            acc[1][0] += a1 * bv.x; acc[1][1] += a1 * bv.y; acc[1][2] += a1 * bv.z; acc[1][3] += a1 * bv.w;
            acc[2][0] += a2 * bv.x; acc[2][1] += a2 * bv.y; acc[2][2] += a2 * bv.z; acc[2][3] += a2 * bv.w;
            acc[3][0] += a3 * bv.x; acc[3][1] += a3 * bv.y; acc[3][2] += a3 * bv.z; acc[3][3] += a3 * bv.w;
        }
        if (tx * 4 < w) {
            const float4 bb = *(const float4*)(b1 + o0 + tx * 4);
            #pragma unroll
            for (int i = 0; i < 4; ++i) {
                int u = ty * 4 + i;
                *(float4*)(pre1 + u * H1 + o0 + tx * 4) =
                    make_float4(acc[i][0] + bb.x, acc[i][1] + bb.y,
                                acc[i][2] + bb.z, acc[i][3] + bb.w);
            }
        }
    } else if (wid == 32) {
        for (int i = tid; i < NN * KDIM; i += NT) Ahat[i] = 0.f;
        __syncthreads();
        if (tid < EE) {
            int s = edge_index[tid], t = edge_index[EE + tid];
            float* row = Ahat + t * KDIM + s * 6;
            #pragma unroll
            for (int d = 0; d < 4; ++d) atomicAdd(row + d, edge_attr[tid * 4 + d]);
            atomicAdd(row + 4, 1.0f);
        }
        if (tid < NN) Ahat[tid * KDIM + tid * 6 + 5] = 1.0f;
    }
    gbar(1, flags, rel, wid >= 0 && wid <= 32, wid >= 0 && wid < 480);

    // ========== S2: n2p[s] = relu(pre1) @ Wcat2, 480 blocks ================
    // grid: s(10) x ot(8) x d(6); span 200 = 5 x KC40
    if (wid >= 0 && wid < 480) {
        const int s = wid % 10, ot = (wid / 10) % 8, d = wid / 80;
        const float* Bsec = (d < 4) ? (We2 + (size_t)d * (H1 * H2))
                                    : ((d == 4) ? be2 : root2);
        const int o0 = ot * 64;
        const int w4 = (o0 + 64 <= H2) ? 16 : ((H2 - o0) >> 2);
        float* As = smem;            // 64 x 44
        float* Bs = smem + 64 * 44;  // 40 x 64
        float acc[4][4] = {};
        for (int it = 0; it < 5; ++it) {
            const int kb = s * 200 + it * 40;
            __syncthreads();
            for (int idx = tid; idx < 640; idx += NT) {
                int r = idx / 10, c4 = idx - r * 10;
                *(float4*)&As[r * 44 + c4 * 4] =
                    relu4(*(const float4*)(pre1 + r * H1 + kb + c4 * 4));
            }
            for (int idx = tid; idx < 640; idx += NT) {
                int k = idx >> 4, c4 = idx & 15;
                if (c4 < w4)
                    *(float4*)&Bs[k * 64 + c4 * 4] =
                        *(const float4*)(Bsec + (size_t)(kb + k) * H2 + o0 + c4 * 4);
            }
            __syncthreads();
            #pragma unroll 8
            for (int kk = 0; kk < 40; ++kk) {
                float a0 = As[(ty * 4 + 0) * 44 + kk];
                float a1 = As[(ty * 4 + 1) * 44 + kk];
                float a2 = As[(ty * 4 + 2) * 44 + kk];
                float a3 = As[(ty * 4 + 3) * 44 + kk];
                const float4 bv = *(const float4*)&Bs[kk * 64 + tx * 4];
                acc[0][0] += a0 * bv.x; acc[0][1] += a0 * bv.y; acc[0][2] += a0 * bv.z; acc[0][3] += a0 * bv.w;
                acc[1][0] += a1 * bv.x; acc[1][1] += a1 * bv.y; acc[1][2] += a1 * bv.z; acc[1][3] += a1 * bv.w;
                acc[2][0] += a2 * bv.x; acc[2][1] += a2 * bv.y; acc[2][2] += a2 * bv.z; acc[2][3] += a2 * bv.w;
                acc[3][0] += a3 * bv.x; acc[3][1] += a3 * bv.y; acc[3][2] += a3 * bv.z; acc[3][3] += a3 * bv.w;
            }
        }
        if (tx < w4) {
            float* dst = n2p + s * (KDIM * H2);
            #pragma unroll
            for (int i = 0; i < 4; ++i) {
                int u = ty * 4 + i;
                *(float4*)(dst + (u * 6 + d) * H2 + o0 + tx * 4) =
                    make_float4(acc[i][0], acc[i][1], acc[i][2], acc[i][3]);
            }
        }
    }
    gbar(2, flags, rel, wid >= 0 && wid < 480, wid >= 0 && wid < 188);

    // ========== T2a: n2 = sum_s n2p[s], 188 blocks streaming ===============
    if (wid >= 0 && wid < 188) {
        int i4 = wid * NT + tid;          // float4 index < 48000
        if (i4 < 48000) {
            const float4* np = (const float4*)n2p;
            float4 a = np[i4];
            #pragma unroll
            for (int s = 1; s < 10; ++s) {
                float4 v = np[s * 48000 + i4];
                a.x += v.x; a.y += v.y; a.z += v.z; a.w += v.w;
            }
            ((float4*)n2)[i4] = a;
        }
    }
    gbar(3, flags, rel, wid >= 0 && wid < 188, wid >= 0 && wid < 32);

    // ========== S3: pre2 = b2 + Ahat @ n2, 32 blocks (ot8 x r4) ============
    if (wid >= 0 && wid < 32) {
        const int ot = wid >> 2, r = wid & 3;
        const int o0 = ot * 64;
        const int w4 = (o0 + 64 <= H2) ? 16 : ((H2 - o0) >> 2);
        float* As = smem;             // 16 x 388
        float* Bs = smem + 16 * 388;  // 48 x 64
        for (int idx = tid; idx < 16 * 96; idx += NT) {
            int rr = idx / 96, c4 = idx - rr * 96;
            *(float4*)&As[rr * 388 + c4 * 4] =
                *(const float4*)(Ahat + (r * 16 + rr) * KDIM + c4 * 4);
        }
        float acc[4] = {};
        for (int it = 0; it < 8; ++it) {
            const int kb = it * 48;
            __syncthreads();
            for (int idx = tid; idx < 48 * 16; idx += NT) {
                int k = idx >> 4, c4 = idx & 15;
                if (c4 < w4)
                    *(float4*)&Bs[k * 64 + c4 * 4] =
                        *(const float4*)(n2 + (kb + k) * H2 + o0 + c4 * 4);
            }
            __syncthreads();
            #pragma unroll 8
            for (int kk = 0; kk < 48; ++kk) {
                float a = As[ty * 388 + kb + kk];
                const float4 bv = *(const float4*)&Bs[kk * 64 + tx * 4];
                acc[0] += a * bv.x; acc[1] += a * bv.y;
                acc[2] += a * bv.z; acc[3] += a * bv.w;
            }
        }
        if (tx < w4) {
            const float4 bb = *(const float4*)(b2 + o0 + tx * 4);
            int u = r * 16 + ty;
            *(float4*)(pre2 + u * H2 + o0 + tx * 4) =
                make_float4(acc[0] + bb.x, acc[1] + bb.y,
                            acc[2] + bb.z, acc[3] + bb.w);
        }
    }
    gbar(4, flags, rel, wid >= 0 && wid < 32, wid >= 0 && wid < 60);

    // ========== S4: n3p[s] = relu(pre2) @ Wcat3, 60 blocks =================
    // grid: s(5) x ot(2) x d(6); span 100 = 5 x KC20
    if (wid >= 0 && wid < 60) {
        const int s = wid % 5, ot = (wid / 5) % 2, d = wid / 10;
        const float* Bsec = (d < 4) ? (We3 + (size_t)d * (H2 * H3))
                                    : ((d == 4) ? be3 : root3);
        const int o0 = ot * 64;
        const int w4 = ot ? 9 : 16;
        float* As = smem;            // 64 x 28
        float* Bs = smem + 64 * 28;  // 20 x 64
        float acc[4][4] = {};
        for (int it = 0; it < 5; ++it) {
            const int kb = s * 100 + it * 20;
            __syncthreads();
            for (int idx = tid; idx < 320; idx += NT) {
                int r = idx / 5, c4 = idx - r * 5;
                *(float4*)&As[r * 28 + c4 * 4] =
                    relu4(*(const float4*)(pre2 + r * H2 + kb + c4 * 4));
            }
            for (int idx = tid; idx < 320; idx += NT) {
                int k = idx >> 4, c4 = idx & 15;
                if (c4 < w4)
                    *(float4*)&Bs[k * 64 + c4 * 4] =
                        *(const float4*)(Bsec + (size_t)(kb + k) * H3 + o0 + c4 * 4);
            }
            __syncthreads();
            #pragma unroll
            for (int kk = 0; kk < 20; ++kk) {
                float a0 = As[(ty * 4 + 0) * 28 + kk];
                float a1 = As[(ty * 4 + 1) * 28 + kk];
                float a2 = As[(ty * 4 + 2) * 28 + kk];
                float a3 = As[(ty * 4 + 3) * 28 + kk];
                const float4 bv = *(const float4*)&Bs[kk * 64 + tx * 4];
                acc[0][0] += a0 * bv.x; acc[0][1] += a0 * bv.y; acc[0][2] += a0 * bv.z; acc[0][3] += a0 * bv.w;
                acc[1][0] += a1 * bv.x; acc[1][1] += a1 * bv.y; acc[1][2] += a1 * bv.z; acc[1][3] += a1 * bv.w;
                acc[2][0] += a2 * bv.x; acc[2][1] += a2 * bv.y; acc[2][2] += a2 * bv.z; acc[2][3] += a2 * bv.w;
                acc[3][0] += a3 * bv.x; acc[3][1] += a3 * bv.y; acc[3][2] += a3 * bv.z; acc[3][3] += a3 * bv.w;
            }
        }
        if (tx < w4) {
            float* dst = n3p + s * (KDIM * H3);
            #pragma unroll
            for (int i = 0; i < 4; ++i) {
                int u = ty * 4 + i;
                *(float4*)(dst + (u * 6 + d) * H3 + o0 + tx * 4) =
                    make_float4(acc[i][0], acc[i][1], acc[i][2], acc[i][3]);
            }
        }
    }
    gbar(5, flags, rel, wid >= 0 && wid < 60, wid >= 0 && wid < 25);

    // ========== T4': g = segsum(relu(b3 + Ahat @ sum_s n3p)), 25 blocks ====
    // Each block owns 4 columns of pre3 (never materialized). 1 out/thread.
    if (wid >= 0 && wid < 25) {
        const int c0 = wid * 4;
        float* Ns  = smem;          // 384*4  summed n3 col-slice
        float* As  = smem + 1536;   // 64*52  Ahat chunk (padded)
        float* Hs  = smem + 4864;   // 256    relu(pre3) values
        int*   bsh = (int*)(smem + 5120);  // 64
        for (int k = tid; k < KDIM; k += NT) {
            float4 a = *(const float4*)(n3p + k * H3 + c0);
            #pragma unroll
            for (int s = 1; s < 5; ++s) {
                float4 v = *(const float4*)(n3p + s * (KDIM * H3) + k * H3 + c0);
                a.x += v.x; a.y += v.y; a.z += v.z; a.w += v.w;
            }
            *(float4*)&Ns[k * 4] = a;
        }
        if (tid < NN) bsh[tid] = batch[tid];
        const int r = tid >> 2, c = tid & 3;
        float acc = b3[c0 + c];
        for (int ch = 0; ch < 8; ++ch) {
            __syncthreads();
            for (int idx = tid; idx < 768; idx += NT) {
                int rr = idx / 12, c4 = idx - rr * 12;
                *(float4*)&As[rr * 52 + c4 * 4] =
                    *(const float4*)(Ahat + rr * KDIM + ch * 48 + c4 * 4);
            }
            __syncthreads();
            #pragma unroll 12
            for (int kk = 0; kk < 48; ++kk)
                acc += As[r * 52 + kk] * Ns[(ch * 48 + kk) * 4 + c];
        }
        Hs[tid] = acc > 0.f ? acc : 0.f;
        __syncthreads();
        if (tid < 16) {
            int gi = tid >> 2, cc = tid & 3;
            float s = 0.f;
            #pragma unroll
            for (int v = 0; v < NN; ++v)
                s += (bsh[v] == gi) ? Hs[v * 4 + cc] : 0.f;
            gw[gi * H3 + c0 + cc] = s;
        }
    }
    gbar(6, flags, rel, wid >= 0 && wid < 25, wid >= 0 && wid < 16);

    // ========== H1: f1-slice + f2 partials, 16 blocks ======================
    if (wid >= 0 && wid < 16) {
        const int k0 = wid * 63;
        const int kn = (k0 + 63 <= FF1) ? 63 : (FF1 - k0);
        float* gs  = smem;        // 400
        float* f1s = smem + 400;  // 4*63
        for (int i = tid; i < GG * H3; i += NT) gs[i] = gw[i];
        __syncthreads();
        for (int idx = tid; idx < GG * kn; idx += NT) {
            int g = idx / kn, kk = idx - g * kn, o = k0 + kk;
            float a = c1[o];
            for (int j = 0; j < H3; ++j)
                a += gs[g * H3 + j] * W1[j * FF1 + o];
            f1s[g * 63 + kk] = a > 0.f ? a : 0.f;
        }
        __syncthreads();
        for (int idx = tid; idx < GG * FF2; idx += NT) {
            int g = idx / FF2, o = idx - g * FF2;
            float a = 0.f;
            for (int kk = 0; kk < kn; ++kk)
                a += f1s[g * 63 + kk] * W2[(k0 + kk) * FF2 + o];
            f2p[wid * 400 + idx] = a;
        }
    }
    gbar(7, flags, rel, wid >= 0 && wid < 16, wid == 0);

    // ========== H2: finish, 1 block ========================================
    if (wid == 0) {
        float* f2s = smem;        // 400
        float* f3s = smem + 400;  // 200
        for (int idx = tid; idx < GG * FF2; idx += NT) {
            float a = c2[idx % FF2];
            #pragma unroll
            for (int p = 0; p < 16; ++p) a += f2p[p * 400 + idx];
            f2s[idx] = a > 0.f ? a : 0.f;
        }
        __syncthreads();
        if (tid < GG * FF3) {
            int g = tid / FF3, o = tid - g * FF3;
            float a = c3[o];
            for (int k = 0; k < FF2; ++k)
                a += f2s[g * FF2 + k] * W3[k * FF3 + o];
            f3s[tid] = a > 0.f ? a : 0.f;
        }
        __syncthreads();
        if (tid < GG) {
            float a = c4[0];
            #pragma unroll
            for (int k = 0; k < FF3; ++k) a += f3s[tid * FF3 + k] * W4[k];
            out[tid] = a;
        }
    }
}

extern "C" void kernel_launch(void* const* d_in, const int* in_sizes, int n_in,
                              void* d_out, int out_size, void* d_ws, size_t ws_size,
                              hipStream_t stream) {
    const float* x          = (const float*)d_in[0];
    const int*   edge_index = (const int*)  d_in[1];
    const float* edge_attr  = (const float*)d_in[2];
    const int*   batch      = (const int*)  d_in[3];
    const float* We1 = (const float*)d_in[4];
    const float* be1 = (const float*)d_in[5];
    const float* root1 = (const float*)d_in[6];
    const float* b1  = (const float*)d_in[7];
    const float* We2 = (const float*)d_in[8];
    const float* be2 = (const float*)d_in[9];
    const float* root2 = (const float*)d_in[10];
    const float* b2  = (const float*)d_in[11];
    const float* We3 = (const float*)d_in[12];
    const float* be3 = (const float*)d_in[13];
    const float* root3 = (const float*)d_in[14];
    const float* b3  = (const float*)d_in[15];
    const float* W1 = (const float*)d_in[16];
    const float* c1 = (const float*)d_in[17];
    const float* W2 = (const float*)d_in[18];
    const float* c2 = (const float*)d_in[19];
    const float* W3 = (const float*)d_in[20];
    const float* c3 = (const float*)d_in[21];
    const float* W4 = (const float*)d_in[22];
    const float* c4 = (const float*)d_in[23];

    fused_gnn<<<GRID, NT, 0, stream>>>(
        x, edge_index, edge_attr, batch,
        We1, be1, root1, b1, We2, be2, root2, b2, We3, be3, root3, b3,
        W1, c1, W2, c2, W3, c3, W4, c4,
        (float*)d_ws, (float*)d_out);
}